// Round 5
// baseline (113.038 us; speedup 1.0000x reference)
//
#include <hip/hip_runtime.h>

#define GH 2048
#define GW 2048
#define OH 2046
#define OW 2046

constexpr int R      = 22;              // output rows per band (reads R+2 rows)
constexpr int BANDS  = 93;              // R * BANDS = 2046
constexpr int CTILES = 33;              // 62 output cols per tile; 33*62 = 2046
constexpr int NWAVES = CTILES * BANDS;  // 3069 wave-tasks -> 12 waves/CU
constexpr int NBLOCKS = (NWAVES + 3) / 4;  // 768 = exactly 3 blocks/CU

__global__ __launch_bounds__(256)
void stencil_kernel(const float* __restrict__ E, const float* __restrict__ v,
                    const float* __restrict__ strain, float2* __restrict__ partials) {
    const int wid  = blockIdx.x * 4 + (threadIdx.x >> 6);
    const int lane = threadIdx.x & 63;
    if (wid >= NWAVES) return;                  // wave-uniform exit
    const int tile = wid % CTILES;
    const int band = wid / CTILES;
    const int col  = tile * 62 + lane;          // max = 32*62+63 = 2047: always in bounds
    const int row0 = band * R;                  // reads rows row0 .. row0+R+1 (max 2047)

    // exactly-once ownership for the E-mean over the full 2048^2 grid
    const bool eown_col = (lane < 62) || (tile == CTILES - 1);
    const int  own_rows = (band == BANDS - 1) ? R + 2 : R;
    const bool out_ok   = (lane < 62);

    float he0=0, he1=0, he2=0, hxx0=0, hxx1=0, hxx2=0, hxy0=0, hxy1=0, hxy2=0;
    float sz0=0, sz1=0, sz2=0, sy0=0, sy1=0, sy2=0;
    float acc = 0.f, eacc = 0.f;

    int idx = row0 * GW + col;                  // row k load address tracker
    // depth-2 software pipeline: n1 = row k+1 data, n2 = row k+2 data
    float e1  = E[idx],          e2  = E[idx + GW];
    float v1  = v[idx],          v2  = v[idx + GW];
    float xx1 = strain[3*idx+0], xx2 = strain[3*(idx+GW)+0];
    float yy1 = strain[3*idx+1], yy2 = strain[3*(idx+GW)+1];
    float xy1 = strain[3*idx+2], xy2 = strain[3*(idx+GW)+2];

    for (int k = 0; k < R + 2; ++k) {
        const float e = e1, vv = v1, exx = xx1, eyy = yy1, exy = xy1;
        e1 = e2; v1 = v2; xx1 = xx2; yy1 = yy2; xy1 = xy2;
        if (k + 2 < R + 2) {                    // prefetch row k+2 (wave-uniform branch)
            const int idx2 = idx + 2 * GW;
            e2  = E[idx2];
            v2  = v[idx2];
            xx2 = strain[3 * idx2 + 0];
            yy2 = strain[3 * idx2 + 1];
            xy2 = strain[3 * idx2 + 2];
        }
        if (eown_col && k < own_rows) eacc += e;

        const float frac = e / (1.f - vv * vv);
        const float sx  = (exx + vv * eyy) * frac;
        const float sy_ = (vv * exx + eyy) * frac;
        const float sz_ = exy * (1.f - vv) * 0.5f * frac;

        const float he_  = e   + __shfl_down(e,   1, 64) + __shfl_down(e,   2, 64);
        const float hxx_ = sx  + __shfl_down(sx,  1, 64) + __shfl_down(sx,  2, 64);
        const float hxy_ = sz_ + __shfl_down(sz_, 1, 64) + __shfl_down(sz_, 2, 64);

        he0 = he1;   he1 = he2;   he2 = he_;
        hxx0 = hxx1; hxx1 = hxx2; hxx2 = hxx_;
        hxy0 = hxy1; hxy1 = hxy2; hxy2 = hxy_;
        sz0 = sz1;   sz1 = sz2;   sz2 = sz_;
        sy0 = sy1;   sy1 = sy2;   sy2 = sy_;

        if (k >= 2) {                           // emit output row (row0 + k - 2)
            const float Vxy = sz0 + sz1 + sz2;
            const float Vyy = sy0 + sy1 + sy2;
            const float fx = (hxx2 - hxx0) + Vxy - __shfl_down(Vxy, 2, 64);
            const float fy = (Vyy - __shfl_down(Vyy, 2, 64)) + (hxy2 - hxy0);
            const float Ec = he0 + he1 + he2;
            const float inv = 1.f / Ec;
            const float c = fabsf(fx * inv) + fabsf(fy * inv);
            acc += out_ok ? c : 0.f;
        }
        idx += GW;
    }

    // intra-wave reduction, one plain store per wave
    #pragma unroll
    for (int off = 32; off > 0; off >>= 1) {
        acc  += __shfl_down(acc,  off, 64);
        eacc += __shfl_down(eacc, off, 64);
    }
    if (lane == 0) partials[wid] = make_float2(acc, eacc);
}

__global__ __launch_bounds__(256)
void finalize_kernel(const float2* __restrict__ partials, float* __restrict__ out) {
    __shared__ double sacc[4][2];
    double a = 0.0, e = 0.0;
    for (int i = threadIdx.x; i < NWAVES; i += 256) {
        float2 p = partials[i];
        a += (double)p.x;
        e += (double)p.y;
    }
    #pragma unroll
    for (int off = 32; off > 0; off >>= 1) {
        a += __shfl_down(a, off, 64);
        e += __shfl_down(e, off, 64);
    }
    const int wave = threadIdx.x >> 6;
    if ((threadIdx.x & 63) == 0) { sacc[wave][0] = a; sacc[wave][1] = e; }
    __syncthreads();
    if (threadIdx.x == 0) {
        double A    = sacc[0][0] + sacc[1][0] + sacc[2][0] + sacc[3][0];
        double Esum = sacc[0][1] + sacc[1][1] + sacc[2][1] + sacc[3][1];
        double M = (double)OH * (double)OW;
        double loss_xy = A / M;
        double loss_e  = fabs(Esum / ((double)GH * (double)GW) - 1.0) / 100.0;
        out[0] = (float)(loss_xy + loss_e);
    }
}

extern "C" void kernel_launch(void* const* d_in, const int* in_sizes, int n_in,
                              void* d_out, int out_size, void* d_ws, size_t ws_size,
                              hipStream_t stream) {
    const float* E      = (const float*)d_in[0];
    const float* v      = (const float*)d_in[1];
    const float* strain = (const float*)d_in[2];
    float* out = (float*)d_out;
    float2* partials = (float2*)d_ws;

    hipLaunchKernelGGL(stencil_kernel, dim3(NBLOCKS), dim3(256), 0, stream,
                       E, v, strain, partials);
    hipLaunchKernelGGL(finalize_kernel, dim3(1), dim3(256), 0, stream, partials, out);
}

// Round 6
// 110.388 us; speedup vs baseline: 1.0240x; 1.0240x over previous
//
#include <hip/hip_runtime.h>

#define GH 2048
#define GW 2048
#define OH 2046
#define OW 2046

constexpr int R      = 11;              // output rows per band (reads R+2 rows)
constexpr int BANDS  = 186;             // R * BANDS = 2046
constexpr int CTILES = 33;              // 62 output cols per tile; 33*62 = 2046
constexpr int NWAVES = CTILES * BANDS;  // 6138 wave-tasks -> ~24 waves/CU
constexpr int NBLOCKS = (NWAVES + 3) / 4;

__global__ __launch_bounds__(256)
void stencil_kernel(const float* __restrict__ E, const float* __restrict__ v,
                    const float* __restrict__ strain, float2* __restrict__ partials) {
    const int wid  = blockIdx.x * 4 + (threadIdx.x >> 6);
    const int lane = threadIdx.x & 63;
    if (wid >= NWAVES) return;                  // wave-uniform exit
    const int tile = wid % CTILES;
    const int band = wid / CTILES;
    const int col  = tile * 62 + lane;          // max = 32*62+63 = 2047: always in bounds
    const int row0 = band * R;                  // reads rows row0 .. row0+R+1 (max 2047)

    // exactly-once ownership for the E-mean over the full 2048^2 grid
    const bool eown_col = (lane < 62) || (tile == CTILES - 1);
    const int  own_rows = (band == BANDS - 1) ? R + 2 : R;
    const bool out_ok   = (lane < 62);

    float he0=0, he1=0, he2=0, hxx0=0, hxx1=0, hxx2=0, hxy0=0, hxy1=0, hxy2=0;
    float sz0=0, sz1=0, sz2=0, sy0=0, sy1=0, sy2=0;
    float acc = 0.f, eacc = 0.f;

    int idx = row0 * GW + col;
    // prefetch row 0
    float e_n  = E[idx];
    float v_n  = v[idx];
    float xx_n = strain[3 * idx + 0];
    float yy_n = strain[3 * idx + 1];
    float xy_n = strain[3 * idx + 2];

    for (int k = 0; k < R + 2; ++k) {
        const float e = e_n, vv = v_n, exx = xx_n, eyy = yy_n, exy = xy_n;
        if (k < R + 1) {                        // prefetch next row while computing this one
            const int idx2 = idx + GW;
            e_n  = E[idx2];
            v_n  = v[idx2];
            xx_n = strain[3 * idx2 + 0];
            yy_n = strain[3 * idx2 + 1];
            xy_n = strain[3 * idx2 + 2];
        }
        if (eown_col && k < own_rows) eacc += e;

        const float frac = e / (1.f - vv * vv);
        const float sx  = (exx + vv * eyy) * frac;
        const float sy_ = (vv * exx + eyy) * frac;
        const float sz_ = exy * (1.f - vv) * 0.5f * frac;

        const float he_  = e   + __shfl_down(e,   1, 64) + __shfl_down(e,   2, 64);
        const float hxx_ = sx  + __shfl_down(sx,  1, 64) + __shfl_down(sx,  2, 64);
        const float hxy_ = sz_ + __shfl_down(sz_, 1, 64) + __shfl_down(sz_, 2, 64);

        he0 = he1;   he1 = he2;   he2 = he_;
        hxx0 = hxx1; hxx1 = hxx2; hxx2 = hxx_;
        hxy0 = hxy1; hxy1 = hxy2; hxy2 = hxy_;
        sz0 = sz1;   sz1 = sz2;   sz2 = sz_;
        sy0 = sy1;   sy1 = sy2;   sy2 = sy_;

        if (k >= 2) {                           // emit output row (row0 + k - 2)
            const float Vxy = sz0 + sz1 + sz2;
            const float Vyy = sy0 + sy1 + sy2;
            const float fx = (hxx2 - hxx0) + Vxy - __shfl_down(Vxy, 2, 64);
            const float fy = (Vyy - __shfl_down(Vyy, 2, 64)) + (hxy2 - hxy0);
            const float Ec = he0 + he1 + he2;
            const float inv = 1.f / Ec;
            const float c = fabsf(fx * inv) + fabsf(fy * inv);
            acc += out_ok ? c : 0.f;
        }
        idx += GW;
    }

    // intra-wave reduction, one plain store per wave
    #pragma unroll
    for (int off = 32; off > 0; off >>= 1) {
        acc  += __shfl_down(acc,  off, 64);
        eacc += __shfl_down(eacc, off, 64);
    }
    if (lane == 0) partials[wid] = make_float2(acc, eacc);
}

__global__ __launch_bounds__(256)
void finalize_kernel(const float2* __restrict__ partials, float* __restrict__ out) {
    __shared__ double sacc[4][2];
    double a = 0.0, e = 0.0;
    for (int i = threadIdx.x; i < NWAVES; i += 256) {
        float2 p = partials[i];
        a += (double)p.x;
        e += (double)p.y;
    }
    #pragma unroll
    for (int off = 32; off > 0; off >>= 1) {
        a += __shfl_down(a, off, 64);
        e += __shfl_down(e, off, 64);
    }
    const int wave = threadIdx.x >> 6;
    if ((threadIdx.x & 63) == 0) { sacc[wave][0] = a; sacc[wave][1] = e; }
    __syncthreads();
    if (threadIdx.x == 0) {
        double A    = sacc[0][0] + sacc[1][0] + sacc[2][0] + sacc[3][0];
        double Esum = sacc[0][1] + sacc[1][1] + sacc[2][1] + sacc[3][1];
        double M = (double)OH * (double)OW;
        double loss_xy = A / M;
        double loss_e  = fabs(Esum / ((double)GH * (double)GW) - 1.0) / 100.0;
        out[0] = (float)(loss_xy + loss_e);
    }
}

extern "C" void kernel_launch(void* const* d_in, const int* in_sizes, int n_in,
                              void* d_out, int out_size, void* d_ws, size_t ws_size,
                              hipStream_t stream) {
    const float* E      = (const float*)d_in[0];
    const float* v      = (const float*)d_in[1];
    const float* strain = (const float*)d_in[2];
    float* out = (float*)d_out;
    float2* partials = (float2*)d_ws;

    hipLaunchKernelGGL(stencil_kernel, dim3(NBLOCKS), dim3(256), 0, stream,
                       E, v, strain, partials);
    hipLaunchKernelGGL(finalize_kernel, dim3(1), dim3(256), 0, stream, partials, out);
}